// Round 2
// baseline (375.472 us; speedup 1.0000x reference)
//
#include <hip/hip_runtime.h>
#include <hip/hip_bf16.h>

#define N_  2
#define C_  256
#define CK_ 32
#define L_  4096

typedef __attribute__((ext_vector_type(8))) short short8;   // 8 bf16 (4 VGPRs)
typedef __attribute__((ext_vector_type(4))) float f32x4;    // MFMA C/D
typedef __attribute__((ext_vector_type(2))) unsigned int uint2v;
typedef unsigned short ushort;

__device__ __forceinline__ ushort f2bf(float f){
  unsigned u = __float_as_uint(f);
  u += 0x7fffu + ((u >> 16) & 1u);     // RNE
  return (ushort)(u >> 16);
}

__device__ __forceinline__ f32x4 mfma16(short8 a, short8 b, f32x4 c){
  return __builtin_amdgcn_mfma_f32_16x16x32_bf16(a, b, c, 0, 0, 0);
}

// ---------- convert+transpose x: [n][C][L] f32 -> [n][L][C] bf16 ----------
// Tile 128c x 64l. float4 reads (1KB/wave), short8 writes (1KB/wave).
__global__ __launch_bounds__(256) void convert_x_kernel(
    const float* __restrict__ x1, const float* __restrict__ x2,
    ushort* __restrict__ xT1, ushort* __restrict__ xT2){
  __shared__ float tt[64][130];        // [l][c], stride 130 (bank stride 2)
  int z = blockIdx.z; int n = z & 1;
  const float* x = (z >> 1) ? x2 : x1;
  ushort* xT = (z >> 1) ? xT2 : xT1;
  int l0 = blockIdx.x * 64, c0 = blockIdx.y * 128;
  int t = threadIdx.x;
  const float* xs = x + (size_t)n * C_ * L_;
  ushort* xd = xT + (size_t)n * L_ * C_;
  int lq = (t & 15) * 4, cl = t >> 4;              // cl 0..15
#pragma unroll
  for (int r = 0; r < 8; ++r){
    int c = r * 16 + cl;
    float4 f = *(const float4*)(xs + (size_t)(c0 + c) * L_ + l0 + lq);
    tt[lq + 0][c] = f.x; tt[lq + 1][c] = f.y; tt[lq + 2][c] = f.z; tt[lq + 3][c] = f.w;
  }
  __syncthreads();
  int c8 = (t & 15) * 8, ll = t >> 4;              // ll 0..15
#pragma unroll
  for (int r = 0; r < 4; ++r){
    int l = r * 16 + ll;
    union { ushort u[8]; short8 v; } pk;
#pragma unroll
    for (int j = 0; j < 8; ++j) pk.u[j] = f2bf(tt[l][c8 + j]);
    *(short8*)(xd + (size_t)(l0 + l) * C_ + c0 + c8) = pk.v;
  }
}

// ---------- convert weights f32 -> bf16 (flat) ----------
__global__ __launch_bounds__(256) void convert_w_kernel(
    const float* __restrict__ Wk1, const float* __restrict__ Wk2,
    const float* __restrict__ Wv1, const float* __restrict__ Wv2,
    ushort* __restrict__ o1, ushort* __restrict__ o2,
    ushort* __restrict__ o3, ushort* __restrict__ o4){
  int idx = blockIdx.x * 256 + threadIdx.x;
  const int KS = CK_ * C_;      // 8192
  const int VS = C_ * C_;       // 65536
  if (idx < KS)                 o1[idx] = f2bf(Wk1[idx]);
  else if (idx < 2*KS)          o2[idx - KS] = f2bf(Wk2[idx - KS]);
  else if (idx < 2*KS + VS)     o3[idx - 2*KS] = f2bf(Wv1[idx - 2*KS]);
  else if (idx < 2*KS + 2*VS)   o4[idx - 2*KS - VS] = f2bf(Wv2[idx - 2*KS - VS]);
}

// ---------- fused projections: k1t/k2t [n][L][CK], v1/v2 [n][C][L] ----------
__global__ __launch_bounds__(256) void proj_kernel(
    const ushort* __restrict__ xT1, const ushort* __restrict__ xT2,
    const ushort* __restrict__ Wk1b, const ushort* __restrict__ Wk2b,
    const ushort* __restrict__ Wv1b, const ushort* __restrict__ Wv2b,
    const float* __restrict__ bk1, const float* __restrict__ bk2,
    const float* __restrict__ bv1, const float* __restrict__ bv2,
    ushort* __restrict__ k1t, ushort* __restrict__ k2t,
    ushort* __restrict__ v1,  ushort* __restrict__ v2){
  int y = blockIdx.y, n = blockIdx.z;
  int t = threadIdx.x, w = t >> 6, lane = t & 63, quad = lane >> 4, low = lane & 15;
  const ushort* X; const ushort* W; const float* bias; ushort* outp; int jt; bool isK;
  if (y < 8)       { X = xT1; W = Wv1b; bias = bv1; outp = v1;  jt = y;     isK = false; }
  else if (y < 16) { X = xT2; W = Wv2b; bias = bv2; outp = v2;  jt = y - 8; isK = false; }
  else if (y == 16){ X = xT1; W = Wk1b; bias = bk1; outp = k1t; jt = 0;     isK = true; }
  else             { X = xT2; W = Wk2b; bias = bk2; outp = k2t; jt = 0;     isK = true; }
  int j0 = jt * 32;
  int l0 = blockIdx.x * 128 + w * 32;
  const ushort* Xn = X + (size_t)n * L_ * C_;
  f32x4 acc[2][2] = {};
#pragma unroll
  for (int kc = 0; kc < 8; ++kc){
    short8 a[2], b[2];
#pragma unroll
    for (int js = 0; js < 2; ++js)
      a[js] = *(const short8*)(W + (size_t)(j0 + js*16 + low)*C_ + kc*32 + quad*8);
#pragma unroll
    for (int ls = 0; ls < 2; ++ls)
      b[ls] = *(const short8*)(Xn + (size_t)(l0 + ls*16 + low)*C_ + kc*32 + quad*8);
#pragma unroll
    for (int js = 0; js < 2; ++js)
#pragma unroll
      for (int ls = 0; ls < 2; ++ls)
        acc[js][ls] = mfma16(a[js], b[ls], acc[js][ls]);
  }
#pragma unroll
  for (int js = 0; js < 2; ++js){
    f32x4 bb = *(const f32x4*)(bias + j0 + js*16 + quad*4);
#pragma unroll
    for (int ls = 0; ls < 2; ++ls){
      int l = l0 + ls*16 + low;
      if (!isK){
#pragma unroll
        for (int r = 0; r < 4; ++r){
          int j = j0 + js*16 + quad*4 + r;
          outp[((size_t)n*C_ + j)*L_ + l] = f2bf(acc[js][ls][r] + bb[r]);
        }
      } else {
        union { ushort u[4]; uint2v v; } pk;
#pragma unroll
        for (int r = 0; r < 4; ++r) pk.u[r] = f2bf(acc[js][ls][r] + bb[r]);
        *(uint2v*)(outp + ((size_t)n*L_ + l)*CK_ + j0 + js*16 + quad*4) = pk.v;
      }
    }
  }
}

// ---------- stats: partial row/col sums of exp(cor) ----------
__global__ __launch_bounds__(256) void stats_kernel(
    const ushort* __restrict__ k1t, const ushort* __restrict__ k2t,
    float* __restrict__ S1part, float* __restrict__ S2part){
  int n = blockIdx.z;
  int m0 = blockIdx.x * 128, l0 = blockIdx.y * 128;
  int t = threadIdx.x, w = t >> 6, lane = t & 63, quad = lane >> 4, low = lane & 15;
  __shared__ float rowsum[128];
  __shared__ float colsum[4][128];
  const ushort* ka = k1t + (size_t)n * L_ * CK_;
  const ushort* kb = k2t + (size_t)n * L_ * CK_;
  short8 a[2], b[8];
#pragma unroll
  for (int lt = 0; lt < 2; ++lt)
    a[lt] = *(const short8*)(ka + (size_t)(l0 + w*32 + lt*16 + low)*CK_ + quad*8);
#pragma unroll
  for (int mt = 0; mt < 8; ++mt)
    b[mt] = *(const short8*)(kb + (size_t)(m0 + mt*16 + low)*CK_ + quad*8);
  float rp[2][4] = {}; float cp[8] = {};
  const f32x4 zero = {0.f, 0.f, 0.f, 0.f};
#pragma unroll
  for (int lt = 0; lt < 2; ++lt)
#pragma unroll
    for (int mt = 0; mt < 8; ++mt){
      f32x4 e = mfma16(a[lt], b[mt], zero);
#pragma unroll
      for (int r = 0; r < 4; ++r){
        float v = __expf(e[r]);
        rp[lt][r] += v;
        cp[mt] += v;
      }
    }
#pragma unroll
  for (int lt = 0; lt < 2; ++lt)
#pragma unroll
    for (int r = 0; r < 4; ++r){
      float v = rp[lt][r];
      v += __shfl_xor(v, 1); v += __shfl_xor(v, 2);
      v += __shfl_xor(v, 4); v += __shfl_xor(v, 8);
      if (low == 0) rowsum[w*32 + lt*16 + quad*4 + r] = v;
    }
#pragma unroll
  for (int mt = 0; mt < 8; ++mt){
    float v = cp[mt];
    v += __shfl_xor(v, 16); v += __shfl_xor(v, 32);
    if (quad == 0) colsum[w][mt*16 + low] = v;
  }
  __syncthreads();
  if (t < 128)
    S1part[((size_t)n*32 + blockIdx.x)*L_ + l0 + t] = rowsum[t];
  else {
    int m = t - 128;
    S2part[((size_t)n*32 + blockIdx.y)*L_ + m0 + m] =
        colsum[0][m] + colsum[1][m] + colsum[2][m] + colsum[3][m];
  }
}

// ---------- reduce partials -> 1/S ----------
__global__ __launch_bounds__(256) void reduce_inv_kernel(
    const float* __restrict__ S1part, const float* __restrict__ S2part,
    float* __restrict__ invS1, float* __restrict__ invS2){
  int idx = blockIdx.x * 256 + threadIdx.x;          // 0..16383
  int which = idx >> 13;
  int r = idx & 8191;                                // n*L + l
  int n = r >> 12, l = r & 4095;
  const float* P = which ? S2part : S1part;
  float s = 0.f;
#pragma unroll
  for (int j = 0; j < 32; ++j) s += P[((size_t)n*32 + j)*L_ + l];
  (which ? invS2 : invS1)[(size_t)n*L_ + l] = 1.0f / s;
}

// ---------- unified flash r-kernel v2 ----------
// out[c,q] = x[c,q] + sum_p v[c,p] * exp(sum_k kA[p,k]*kB[q,k]) * invS[p]
// Tile: c=256 (full C, E-recompute ratio 12.5%), q=16.
// grid (L/16=256, 4) = 1024 blocks -> 8 blocks/CU, 32 waves/CU.
// Double-buffered ptile: ONE barrier per 128-p chunk.
__global__ __launch_bounds__(256, 8) void cross_attn_r_kernel(
    const ushort* __restrict__ k1t, const ushort* __restrict__ k2t,
    const ushort* __restrict__ v1,  const ushort* __restrict__ v2,
    const float* __restrict__ invS1, const float* __restrict__ invS2,
    const float* __restrict__ x1, const float* __restrict__ x2,
    float* __restrict__ out){
  int z = blockIdx.y; int which = z >> 1; int n = z & 1;
  const ushort* kA = which ? k2t : k1t;
  const ushort* kB = which ? k1t : k2t;
  const ushort* V  = which ? v2  : v1;
  const float* iS  = which ? invS2 : invS1;
  const float* X   = which ? x2 : x1;
  float* O = out + (size_t)which * N_ * C_ * L_;
  int q0 = blockIdx.x * 16;
  int t = threadIdx.x, w = t >> 6, lane = t & 63, quad = lane >> 4, low = lane & 15;
  __shared__ __align__(16) ushort ptile[2][16][136];   // [buf][q][p]
  const ushort* kAn = kA + (size_t)n * L_ * CK_;
  const ushort* kBn = kB + (size_t)n * L_ * CK_;
  const ushort* Vn  = V  + (size_t)n * C_ * L_;
  const float*  iSn = iS + (size_t)n * L_;
  // B operand of E-MFMA (q rows of kB) is chunk-invariant: preload once.
  short8 be = *(const short8*)(kBn + (size_t)(q0 + low) * CK_ + quad * 8);
  f32x4 acc[4] = {};
  const f32x4 zero = {0.f, 0.f, 0.f, 0.f};
  for (int k = 0; k < L_ / 128; ++k){
    int p0 = k * 128;
    ushort (*buf)[136] = ptile[k & 1];
    // --- E phase: this wave computes p-rows [w*32, w*32+32) of the chunk
#pragma unroll
    for (int ps = 0; ps < 2; ++ps){
      int pr = w * 32 + ps * 16;
      short8 a = *(const short8*)(kAn + (size_t)(p0 + pr + low) * CK_ + quad * 8);
      f32x4 sv = *(const f32x4*)(iSn + p0 + pr + quad * 4);
      f32x4 e = mfma16(a, be, zero);
      union { __hip_bfloat162 h[2]; uint2v v; } pk;
      pk.h[0] = __float22bfloat162_rn(make_float2(__expf(e[0]) * sv[0], __expf(e[1]) * sv[1]));
      pk.h[1] = __float22bfloat162_rn(make_float2(__expf(e[2]) * sv[2], __expf(e[3]) * sv[3]));
      *(uint2v*)&buf[low][pr + quad * 4] = pk.v;
    }
    __syncthreads();
    // --- main phase: acc[c,q] += V[c,p] * P[p,q]; wave owns c-rows w*64..w*64+63
#pragma unroll
    for (int ks = 0; ks < 4; ++ks){
      short8 bb = *(const short8*)&buf[low][ks * 32 + quad * 8];
#pragma unroll
      for (int cs = 0; cs < 4; ++cs){
        short8 av = *(const short8*)(Vn + (size_t)(w * 64 + cs * 16 + low) * L_ + p0 + ks * 32 + quad * 8);
        acc[cs] = mfma16(av, bb, acc[cs]);
      }
    }
  }
  // --- epilogue: out = x + acc
#pragma unroll
  for (int cs = 0; cs < 4; ++cs){
    int cb = w * 64 + cs * 16 + quad * 4;
#pragma unroll
    for (int r = 0; r < 4; ++r){
      size_t idx = ((size_t)n * C_ + cb + r) * L_ + q0 + low;
      O[idx] = X[idx] + acc[cs][r];
    }
  }
}

extern "C" void kernel_launch(void* const* d_in, const int* in_sizes, int n_in,
                              void* d_out, int out_size, void* d_ws, size_t ws_size,
                              hipStream_t stream) {
  const float* x1  = (const float*)d_in[0];
  const float* x2  = (const float*)d_in[1];
  const float* Wk1 = (const float*)d_in[2];
  const float* bk1 = (const float*)d_in[3];
  const float* Wk2 = (const float*)d_in[4];
  const float* bk2 = (const float*)d_in[5];
  const float* Wv1 = (const float*)d_in[6];
  const float* bv1 = (const float*)d_in[7];
  const float* Wv2 = (const float*)d_in[8];
  const float* bv2 = (const float*)d_in[9];

  char* ws = (char*)d_ws;
  size_t off = 0;
  auto carve = [&](size_t bytes) -> void* {
    void* p = ws + off; off += (bytes + 255) & ~(size_t)255; return p;
  };
  ushort* xT1   = (ushort*)carve((size_t)N_*L_*C_*2);
  ushort* xT2   = (ushort*)carve((size_t)N_*L_*C_*2);
  ushort* Wk1b  = (ushort*)carve((size_t)CK_*C_*2);
  ushort* Wk2b  = (ushort*)carve((size_t)CK_*C_*2);
  ushort* Wv1b  = (ushort*)carve((size_t)C_*C_*2);
  ushort* Wv2b  = (ushort*)carve((size_t)C_*C_*2);
  ushort* k1t   = (ushort*)carve((size_t)N_*L_*CK_*2);
  ushort* k2t   = (ushort*)carve((size_t)N_*L_*CK_*2);
  ushort* v1    = (ushort*)carve((size_t)N_*C_*L_*2);
  ushort* v2    = (ushort*)carve((size_t)N_*C_*L_*2);
  float*  S1p   = (float*)carve((size_t)N_*32*L_*4);
  float*  S2p   = (float*)carve((size_t)N_*32*L_*4);
  float*  invS1 = (float*)carve((size_t)N_*L_*4);
  float*  invS2 = (float*)carve((size_t)N_*L_*4);

  convert_x_kernel<<<dim3(L_/64, C_/128, 4), 256, 0, stream>>>(x1, x2, xT1, xT2);
  convert_w_kernel<<<dim3((2*CK_*C_ + 2*C_*C_) / 256), 256, 0, stream>>>(
      Wk1, Wk2, Wv1, Wv2, Wk1b, Wk2b, Wv1b, Wv2b);
  proj_kernel<<<dim3(L_/128, 18, N_), 256, 0, stream>>>(
      xT1, xT2, Wk1b, Wk2b, Wv1b, Wv2b, bk1, bk2, bv1, bv2, k1t, k2t, v1, v2);
  stats_kernel<<<dim3(L_/128, L_/128, N_), 256, 0, stream>>>(k1t, k2t, S1p, S2p);
  reduce_inv_kernel<<<dim3(2*N_*L_/256), 256, 0, stream>>>(S1p, S2p, invS1, invS2);
  cross_attn_r_kernel<<<dim3(L_/16, 2*N_), 256, 0, stream>>>(
      k1t, k2t, v1, v2, invS1, invS2, x1, x2, (float*)d_out);
}

// Round 3
// 203.134 us; speedup vs baseline: 1.8484x; 1.8484x over previous
//
#include <hip/hip_runtime.h>
#include <hip/hip_bf16.h>

#define N_  2
#define C_  256
#define CK_ 32
#define L_  4096

typedef __attribute__((ext_vector_type(8))) short short8;   // 8 bf16 (4 VGPRs)
typedef __attribute__((ext_vector_type(4))) float f32x4;    // MFMA C/D
typedef __attribute__((ext_vector_type(2))) unsigned int uint2v;
typedef unsigned short ushort;

__device__ __forceinline__ ushort f2bf(float f){
  unsigned u = __float_as_uint(f);
  u += 0x7fffu + ((u >> 16) & 1u);     // RNE
  return (ushort)(u >> 16);
}

__device__ __forceinline__ f32x4 mfma16(short8 a, short8 b, f32x4 c){
  return __builtin_amdgcn_mfma_f32_16x16x32_bf16(a, b, c, 0, 0, 0);
}

// ---------- convert+transpose x: [n][C][L] f32 -> [n][L][C] bf16 ----------
__global__ __launch_bounds__(256) void convert_x_kernel(
    const float* __restrict__ x1, const float* __restrict__ x2,
    ushort* __restrict__ xT1, ushort* __restrict__ xT2){
  __shared__ float tt[64][130];        // [l][c]
  int z = blockIdx.z; int n = z & 1;
  const float* x = (z >> 1) ? x2 : x1;
  ushort* xT = (z >> 1) ? xT2 : xT1;
  int l0 = blockIdx.x * 64, c0 = blockIdx.y * 128;
  int t = threadIdx.x;
  const float* xs = x + (size_t)n * C_ * L_;
  ushort* xd = xT + (size_t)n * L_ * C_;
  int lq = (t & 15) * 4, cl = t >> 4;              // cl 0..15
#pragma unroll
  for (int r = 0; r < 8; ++r){
    int c = r * 16 + cl;
    float4 f = *(const float4*)(xs + (size_t)(c0 + c) * L_ + l0 + lq);
    tt[lq + 0][c] = f.x; tt[lq + 1][c] = f.y; tt[lq + 2][c] = f.z; tt[lq + 3][c] = f.w;
  }
  __syncthreads();
  int c8 = (t & 15) * 8, ll = t >> 4;              // ll 0..15
#pragma unroll
  for (int r = 0; r < 4; ++r){
    int l = r * 16 + ll;
    union { ushort u[8]; short8 v; } pk;
#pragma unroll
    for (int j = 0; j < 8; ++j) pk.u[j] = f2bf(tt[l][c8 + j]);
    *(short8*)(xd + (size_t)(l0 + l) * C_ + c0 + c8) = pk.v;
  }
}

// ---------- convert weights f32 -> bf16 (flat) ----------
__global__ __launch_bounds__(256) void convert_w_kernel(
    const float* __restrict__ Wk1, const float* __restrict__ Wk2,
    const float* __restrict__ Wv1, const float* __restrict__ Wv2,
    ushort* __restrict__ o1, ushort* __restrict__ o2,
    ushort* __restrict__ o3, ushort* __restrict__ o4){
  int idx = blockIdx.x * 256 + threadIdx.x;
  const int KS = CK_ * C_;      // 8192
  const int VS = C_ * C_;       // 65536
  if (idx < KS)                 o1[idx] = f2bf(Wk1[idx]);
  else if (idx < 2*KS)          o2[idx - KS] = f2bf(Wk2[idx - KS]);
  else if (idx < 2*KS + VS)     o3[idx - 2*KS] = f2bf(Wv1[idx - 2*KS]);
  else if (idx < 2*KS + 2*VS)   o4[idx - 2*KS - VS] = f2bf(Wv2[idx - 2*KS - VS]);
}

// ---------- fused projections: k1t/k2t [n][L][CK], v1/v2 [n][C][L] ----------
__global__ __launch_bounds__(256) void proj_kernel(
    const ushort* __restrict__ xT1, const ushort* __restrict__ xT2,
    const ushort* __restrict__ Wk1b, const ushort* __restrict__ Wk2b,
    const ushort* __restrict__ Wv1b, const ushort* __restrict__ Wv2b,
    const float* __restrict__ bk1, const float* __restrict__ bk2,
    const float* __restrict__ bv1, const float* __restrict__ bv2,
    ushort* __restrict__ k1t, ushort* __restrict__ k2t,
    ushort* __restrict__ v1,  ushort* __restrict__ v2){
  int y = blockIdx.y, n = blockIdx.z;
  int t = threadIdx.x, w = t >> 6, lane = t & 63, quad = lane >> 4, low = lane & 15;
  const ushort* X; const ushort* W; const float* bias; ushort* outp; int jt; bool isK;
  if (y < 8)       { X = xT1; W = Wv1b; bias = bv1; outp = v1;  jt = y;     isK = false; }
  else if (y < 16) { X = xT2; W = Wv2b; bias = bv2; outp = v2;  jt = y - 8; isK = false; }
  else if (y == 16){ X = xT1; W = Wk1b; bias = bk1; outp = k1t; jt = 0;     isK = true; }
  else             { X = xT2; W = Wk2b; bias = bk2; outp = k2t; jt = 0;     isK = true; }
  int j0 = jt * 32;
  int l0 = blockIdx.x * 128 + w * 32;
  const ushort* Xn = X + (size_t)n * L_ * C_;
  f32x4 acc[2][2] = {};
#pragma unroll
  for (int kc = 0; kc < 8; ++kc){
    short8 a[2], b[2];
#pragma unroll
    for (int js = 0; js < 2; ++js)
      a[js] = *(const short8*)(W + (size_t)(j0 + js*16 + low)*C_ + kc*32 + quad*8);
#pragma unroll
    for (int ls = 0; ls < 2; ++ls)
      b[ls] = *(const short8*)(Xn + (size_t)(l0 + ls*16 + low)*C_ + kc*32 + quad*8);
#pragma unroll
    for (int js = 0; js < 2; ++js)
#pragma unroll
      for (int ls = 0; ls < 2; ++ls)
        acc[js][ls] = mfma16(a[js], b[ls], acc[js][ls]);
  }
#pragma unroll
  for (int js = 0; js < 2; ++js){
    f32x4 bb = *(const f32x4*)(bias + j0 + js*16 + quad*4);
#pragma unroll
    for (int ls = 0; ls < 2; ++ls){
      int l = l0 + ls*16 + low;
      if (!isK){
#pragma unroll
        for (int r = 0; r < 4; ++r){
          int j = j0 + js*16 + quad*4 + r;
          outp[((size_t)n*C_ + j)*L_ + l] = f2bf(acc[js][ls][r] + bb[r]);
        }
      } else {
        union { ushort u[4]; uint2v v; } pk;
#pragma unroll
        for (int r = 0; r < 4; ++r) pk.u[r] = f2bf(acc[js][ls][r] + bb[r]);
        *(uint2v*)(outp + ((size_t)n*L_ + l)*CK_ + j0 + js*16 + quad*4) = pk.v;
      }
    }
  }
}

// ---------- stats: partial row/col sums of exp(cor) ----------
__global__ __launch_bounds__(256) void stats_kernel(
    const ushort* __restrict__ k1t, const ushort* __restrict__ k2t,
    float* __restrict__ S1part, float* __restrict__ S2part){
  int n = blockIdx.z;
  int m0 = blockIdx.x * 128, l0 = blockIdx.y * 128;
  int t = threadIdx.x, w = t >> 6, lane = t & 63, quad = lane >> 4, low = lane & 15;
  __shared__ float rowsum[128];
  __shared__ float colsum[4][128];
  const ushort* ka = k1t + (size_t)n * L_ * CK_;
  const ushort* kb = k2t + (size_t)n * L_ * CK_;
  short8 a[2], b[8];
#pragma unroll
  for (int lt = 0; lt < 2; ++lt)
    a[lt] = *(const short8*)(ka + (size_t)(l0 + w*32 + lt*16 + low)*CK_ + quad*8);
#pragma unroll
  for (int mt = 0; mt < 8; ++mt)
    b[mt] = *(const short8*)(kb + (size_t)(m0 + mt*16 + low)*CK_ + quad*8);
  float rp[2][4] = {}; float cp[8] = {};
  const f32x4 zero = {0.f, 0.f, 0.f, 0.f};
#pragma unroll
  for (int lt = 0; lt < 2; ++lt)
#pragma unroll
    for (int mt = 0; mt < 8; ++mt){
      f32x4 e = mfma16(a[lt], b[mt], zero);
#pragma unroll
      for (int r = 0; r < 4; ++r){
        float v = __expf(e[r]);
        rp[lt][r] += v;
        cp[mt] += v;
      }
    }
#pragma unroll
  for (int lt = 0; lt < 2; ++lt)
#pragma unroll
    for (int r = 0; r < 4; ++r){
      float v = rp[lt][r];
      v += __shfl_xor(v, 1); v += __shfl_xor(v, 2);
      v += __shfl_xor(v, 4); v += __shfl_xor(v, 8);
      if (low == 0) rowsum[w*32 + lt*16 + quad*4 + r] = v;
    }
#pragma unroll
  for (int mt = 0; mt < 8; ++mt){
    float v = cp[mt];
    v += __shfl_xor(v, 16); v += __shfl_xor(v, 32);
    if (quad == 0) colsum[w][mt*16 + low] = v;
  }
  __syncthreads();
  if (t < 128)
    S1part[((size_t)n*32 + blockIdx.x)*L_ + l0 + t] = rowsum[t];
  else {
    int m = t - 128;
    S2part[((size_t)n*32 + blockIdx.y)*L_ + m0 + m] =
        colsum[0][m] + colsum[1][m] + colsum[2][m] + colsum[3][m];
  }
}

// ---------- reduce partials -> 1/S ----------
__global__ __launch_bounds__(256) void reduce_inv_kernel(
    const float* __restrict__ S1part, const float* __restrict__ S2part,
    float* __restrict__ invS1, float* __restrict__ invS2){
  int idx = blockIdx.x * 256 + threadIdx.x;          // 0..16383
  int which = idx >> 13;
  int r = idx & 8191;                                // n*L + l
  int n = r >> 12, l = r & 4095;
  const float* P = which ? S2part : S1part;
  float s = 0.f;
#pragma unroll
  for (int j = 0; j < 32; ++j) s += P[((size_t)n*32 + j)*L_ + l];
  (which ? invS2 : invS1)[(size_t)n*L_ + l] = 1.0f / s;
}

// ---------- unified flash r-kernel v3 ----------
// out[c,q] = x[c,q] + sum_p v[c,p] * exp(sum_k kA[p,k]*kB[q,k]) * invS[p]
// Tile: q=64, c=128. grid (64, 2, 4) = 512 blocks, 2/CU, 8 waves/CU.
// p-chunk=128; double-buffered ptile, ONE barrier per chunk; one-chunk-ahead
// register prefetch of kA/invS/V (parity arrays) so post-barrier work is
// pure LDS+MFMA. launch_bounds(256,2) -> 256-VGPR budget (round-2's
// (256,8)->32 VGPRs serialized all loads; never again).
__global__ __launch_bounds__(256, 2) void cross_attn_r_kernel(
    const ushort* __restrict__ k1t, const ushort* __restrict__ k2t,
    const ushort* __restrict__ v1,  const ushort* __restrict__ v2,
    const float* __restrict__ invS1, const float* __restrict__ invS2,
    const float* __restrict__ x1, const float* __restrict__ x2,
    float* __restrict__ out){
  int z = blockIdx.z; int which = z >> 1; int n = z & 1;
  const ushort* kA = which ? k2t : k1t;
  const ushort* kB = which ? k1t : k2t;
  const ushort* V  = which ? v2  : v1;
  const float* iS  = which ? invS2 : invS1;
  const float* X   = which ? x2 : x1;
  float* O = out + (size_t)which * N_ * C_ * L_;
  int q0 = blockIdx.x * 64, c0 = blockIdx.y * 128;
  int t = threadIdx.x, w = t >> 6, lane = t & 63, quad = lane >> 4, low = lane & 15;
  __shared__ __align__(16) ushort ptile[2][64][144];   // rows 288B: 16B-aligned, 4-way-max banks
  const ushort* kAn = kA + (size_t)n * L_ * CK_;
  const ushort* kBn = kB + (size_t)n * L_ * CK_;
  const ushort* Vn  = V  + (size_t)n * C_ * L_;
  const float*  iSn = iS + (size_t)n * L_;
  // E-phase B operand (q rows of kB) is chunk-invariant: preload once.
  short8 be[4];
#pragma unroll
  for (int qs = 0; qs < 4; ++qs)
    be[qs] = *(const short8*)(kBn + (size_t)(q0 + qs*16 + low) * CK_ + quad * 8);
  f32x4 acc[2][4] = {};
  const f32x4 zero = {0.f, 0.f, 0.f, 0.f};
  // parity-indexed prefetch state
  short8 a[2][2]; f32x4 sv[2][2]; short8 vv[2][4][2];
#pragma unroll
  for (int ps = 0; ps < 2; ++ps){
    a[0][ps]  = *(const short8*)(kAn + (size_t)(w*32 + ps*16 + low) * CK_ + quad * 8);
    sv[0][ps] = *(const f32x4*)(iSn + w*32 + ps*16 + quad*4);
  }
#pragma unroll
  for (int ks = 0; ks < 4; ++ks)
#pragma unroll
    for (int cs = 0; cs < 2; ++cs)
      vv[0][ks][cs] = *(const short8*)(Vn + (size_t)(c0 + w*32 + cs*16 + low) * L_ + ks*32 + quad*8);

#pragma unroll 2
  for (int k = 0; k < L_ / 128; ++k){
    int cur = k & 1, nxt = cur ^ 1;
    ushort (*buf)[144] = ptile[cur];
    // --- E phase: P chunk rows w*32..w*32+31 -> LDS transposed [q][p]
#pragma unroll
    for (int ps = 0; ps < 2; ++ps){
#pragma unroll
      for (int qs = 0; qs < 4; ++qs){
        f32x4 e = mfma16(a[cur][ps], be[qs], zero);
        union { __hip_bfloat162 h[2]; uint2v v; } pk;
        pk.h[0] = __float22bfloat162_rn(make_float2(__expf(e[0]) * sv[cur][ps][0],
                                                    __expf(e[1]) * sv[cur][ps][1]));
        pk.h[1] = __float22bfloat162_rn(make_float2(__expf(e[2]) * sv[cur][ps][2],
                                                    __expf(e[3]) * sv[cur][ps][3]));
        *(uint2v*)&buf[qs*16 + low][w*32 + ps*16 + quad*4] = pk.v;
      }
    }
    // --- prefetch chunk k+1 (wrapped in-bounds; last-iter values unused)
    int pn = ((k + 1) & 31) * 128;
#pragma unroll
    for (int ps = 0; ps < 2; ++ps){
      a[nxt][ps]  = *(const short8*)(kAn + (size_t)(pn + w*32 + ps*16 + low) * CK_ + quad * 8);
      sv[nxt][ps] = *(const f32x4*)(iSn + pn + w*32 + ps*16 + quad*4);
    }
#pragma unroll
    for (int ks = 0; ks < 4; ++ks)
#pragma unroll
      for (int cs = 0; cs < 2; ++cs)
        vv[nxt][ks][cs] = *(const short8*)(Vn + (size_t)(c0 + w*32 + cs*16 + low) * L_ + pn + ks*32 + quad*8);
    __syncthreads();
    // --- main phase: acc[c,q] += V[c,p] * P[p,q]
#pragma unroll
    for (int ks = 0; ks < 4; ++ks){
      short8 bb[4];
#pragma unroll
      for (int qs = 0; qs < 4; ++qs)
        bb[qs] = *(const short8*)&buf[qs*16 + low][ks*32 + quad*8];
#pragma unroll
      for (int cs = 0; cs < 2; ++cs)
#pragma unroll
        for (int qs = 0; qs < 4; ++qs)
          acc[cs][qs] = mfma16(vv[cur][ks][cs], bb[qs], acc[cs][qs]);
    }
  }
  // --- epilogue: out = x + acc
#pragma unroll
  for (int cs = 0; cs < 2; ++cs)
#pragma unroll
    for (int qs = 0; qs < 4; ++qs){
      int cb = c0 + w*32 + cs*16 + quad*4;
      int q = q0 + qs*16 + low;
#pragma unroll
      for (int r = 0; r < 4; ++r){
        size_t idx = ((size_t)n * C_ + cb + r) * L_ + q;
        O[idx] = X[idx] + acc[cs][qs][r];
      }
    }
}

extern "C" void kernel_launch(void* const* d_in, const int* in_sizes, int n_in,
                              void* d_out, int out_size, void* d_ws, size_t ws_size,
                              hipStream_t stream) {
  const float* x1  = (const float*)d_in[0];
  const float* x2  = (const float*)d_in[1];
  const float* Wk1 = (const float*)d_in[2];
  const float* bk1 = (const float*)d_in[3];
  const float* Wk2 = (const float*)d_in[4];
  const float* bk2 = (const float*)d_in[5];
  const float* Wv1 = (const float*)d_in[6];
  const float* bv1 = (const float*)d_in[7];
  const float* Wv2 = (const float*)d_in[8];
  const float* bv2 = (const float*)d_in[9];

  char* ws = (char*)d_ws;
  size_t off = 0;
  auto carve = [&](size_t bytes) -> void* {
    void* p = ws + off; off += (bytes + 255) & ~(size_t)255; return p;
  };
  ushort* xT1   = (ushort*)carve((size_t)N_*L_*C_*2);
  ushort* xT2   = (ushort*)carve((size_t)N_*L_*C_*2);
  ushort* Wk1b  = (ushort*)carve((size_t)CK_*C_*2);
  ushort* Wk2b  = (ushort*)carve((size_t)CK_*C_*2);
  ushort* Wv1b  = (ushort*)carve((size_t)C_*C_*2);
  ushort* Wv2b  = (ushort*)carve((size_t)C_*C_*2);
  ushort* k1t   = (ushort*)carve((size_t)N_*L_*CK_*2);
  ushort* k2t   = (ushort*)carve((size_t)N_*L_*CK_*2);
  ushort* v1    = (ushort*)carve((size_t)N_*C_*L_*2);
  ushort* v2    = (ushort*)carve((size_t)N_*C_*L_*2);
  float*  S1p   = (float*)carve((size_t)N_*32*L_*4);
  float*  S2p   = (float*)carve((size_t)N_*32*L_*4);
  float*  invS1 = (float*)carve((size_t)N_*L_*4);
  float*  invS2 = (float*)carve((size_t)N_*L_*4);

  convert_x_kernel<<<dim3(L_/64, C_/128, 4), 256, 0, stream>>>(x1, x2, xT1, xT2);
  convert_w_kernel<<<dim3((2*CK_*C_ + 2*C_*C_) / 256), 256, 0, stream>>>(
      Wk1, Wk2, Wv1, Wv2, Wk1b, Wk2b, Wv1b, Wv2b);
  proj_kernel<<<dim3(L_/128, 18, N_), 256, 0, stream>>>(
      xT1, xT2, Wk1b, Wk2b, Wv1b, Wv2b, bk1, bk2, bv1, bv2, k1t, k2t, v1, v2);
  stats_kernel<<<dim3(L_/128, L_/128, N_), 256, 0, stream>>>(k1t, k2t, S1p, S2p);
  reduce_inv_kernel<<<dim3(2*N_*L_/256), 256, 0, stream>>>(S1p, S2p, invS1, invS2);
  cross_attn_r_kernel<<<dim3(L_/64, C_/128, 2*N_), 256, 0, stream>>>(
      k1t, k2t, v1, v2, invS1, invS2, x1, x2, (float*)d_out);
}

// Round 5
// 199.362 us; speedup vs baseline: 1.8834x; 1.0189x over previous
//
#include <hip/hip_runtime.h>
#include <hip/hip_bf16.h>

#define N_  2
#define C_  256
#define CK_ 32
#define L_  4096

typedef __attribute__((ext_vector_type(8))) short short8;   // 8 bf16 (4 VGPRs)
typedef __attribute__((ext_vector_type(4))) float f32x4;    // MFMA C/D
typedef __attribute__((ext_vector_type(2))) unsigned int uint2v;
typedef unsigned short ushort;

__device__ __forceinline__ ushort f2bf(float f){
  unsigned u = __float_as_uint(f);
  u += 0x7fffu + ((u >> 16) & 1u);     // RNE
  return (ushort)(u >> 16);
}

__device__ __forceinline__ f32x4 mfma16(short8 a, short8 b, f32x4 c){
  return __builtin_amdgcn_mfma_f32_16x16x32_bf16(a, b, c, 0, 0, 0);
}

// ---------- convert+transpose x: [n][C][L] f32 -> [n][L][C] bf16 ----------
__global__ __launch_bounds__(256) void convert_x_kernel(
    const float* __restrict__ x1, const float* __restrict__ x2,
    ushort* __restrict__ xT1, ushort* __restrict__ xT2){
  __shared__ float tt[64][130];        // [l][c]
  int z = blockIdx.z; int n = z & 1;
  const float* x = (z >> 1) ? x2 : x1;
  ushort* xT = (z >> 1) ? xT2 : xT1;
  int l0 = blockIdx.x * 64, c0 = blockIdx.y * 128;
  int t = threadIdx.x;
  const float* xs = x + (size_t)n * C_ * L_;
  ushort* xd = xT + (size_t)n * L_ * C_;
  int lq = (t & 15) * 4, cl = t >> 4;              // cl 0..15
#pragma unroll
  for (int r = 0; r < 8; ++r){
    int c = r * 16 + cl;
    float4 f = *(const float4*)(xs + (size_t)(c0 + c) * L_ + l0 + lq);
    tt[lq + 0][c] = f.x; tt[lq + 1][c] = f.y; tt[lq + 2][c] = f.z; tt[lq + 3][c] = f.w;
  }
  __syncthreads();
  int c8 = (t & 15) * 8, ll = t >> 4;              // ll 0..15
#pragma unroll
  for (int r = 0; r < 4; ++r){
    int l = r * 16 + ll;
    union { ushort u[8]; short8 v; } pk;
#pragma unroll
    for (int j = 0; j < 8; ++j) pk.u[j] = f2bf(tt[l][c8 + j]);
    *(short8*)(xd + (size_t)(l0 + l) * C_ + c0 + c8) = pk.v;
  }
}

// ---------- convert weights f32 -> bf16 (flat) ----------
__global__ __launch_bounds__(256) void convert_w_kernel(
    const float* __restrict__ Wk1, const float* __restrict__ Wk2,
    const float* __restrict__ Wv1, const float* __restrict__ Wv2,
    ushort* __restrict__ o1, ushort* __restrict__ o2,
    ushort* __restrict__ o3, ushort* __restrict__ o4){
  int idx = blockIdx.x * 256 + threadIdx.x;
  const int KS = CK_ * C_;      // 8192
  const int VS = C_ * C_;       // 65536
  if (idx < KS)                 o1[idx] = f2bf(Wk1[idx]);
  else if (idx < 2*KS)          o2[idx - KS] = f2bf(Wk2[idx - KS]);
  else if (idx < 2*KS + VS)     o3[idx - 2*KS] = f2bf(Wv1[idx - 2*KS]);
  else if (idx < 2*KS + 2*VS)   o4[idx - 2*KS - VS] = f2bf(Wv2[idx - 2*KS - VS]);
}

// ---------- fused projections: k1t/k2t [n][L][CK], v1/v2 [n][C][L] ----------
__global__ __launch_bounds__(256) void proj_kernel(
    const ushort* __restrict__ xT1, const ushort* __restrict__ xT2,
    const ushort* __restrict__ Wk1b, const ushort* __restrict__ Wk2b,
    const ushort* __restrict__ Wv1b, const ushort* __restrict__ Wv2b,
    const float* __restrict__ bk1, const float* __restrict__ bk2,
    const float* __restrict__ bv1, const float* __restrict__ bv2,
    ushort* __restrict__ k1t, ushort* __restrict__ k2t,
    ushort* __restrict__ v1,  ushort* __restrict__ v2){
  int y = blockIdx.y, n = blockIdx.z;
  int t = threadIdx.x, w = t >> 6, lane = t & 63, quad = lane >> 4, low = lane & 15;
  const ushort* X; const ushort* W; const float* bias; ushort* outp; int jt; bool isK;
  if (y < 8)       { X = xT1; W = Wv1b; bias = bv1; outp = v1;  jt = y;     isK = false; }
  else if (y < 16) { X = xT2; W = Wv2b; bias = bv2; outp = v2;  jt = y - 8; isK = false; }
  else if (y == 16){ X = xT1; W = Wk1b; bias = bk1; outp = k1t; jt = 0;     isK = true; }
  else             { X = xT2; W = Wk2b; bias = bk2; outp = k2t; jt = 0;     isK = true; }
  int j0 = jt * 32;
  int l0 = blockIdx.x * 128 + w * 32;
  const ushort* Xn = X + (size_t)n * L_ * C_;
  f32x4 acc[2][2] = {};
#pragma unroll
  for (int kc = 0; kc < 8; ++kc){
    short8 a[2], b[2];
#pragma unroll
    for (int js = 0; js < 2; ++js)
      a[js] = *(const short8*)(W + (size_t)(j0 + js*16 + low)*C_ + kc*32 + quad*8);
#pragma unroll
    for (int ls = 0; ls < 2; ++ls)
      b[ls] = *(const short8*)(Xn + (size_t)(l0 + ls*16 + low)*C_ + kc*32 + quad*8);
#pragma unroll
    for (int js = 0; js < 2; ++js)
#pragma unroll
      for (int ls = 0; ls < 2; ++ls)
        acc[js][ls] = mfma16(a[js], b[ls], acc[js][ls]);
  }
#pragma unroll
  for (int js = 0; js < 2; ++js){
    f32x4 bb = *(const f32x4*)(bias + j0 + js*16 + quad*4);
#pragma unroll
    for (int ls = 0; ls < 2; ++ls){
      int l = l0 + ls*16 + low;
      if (!isK){
#pragma unroll
        for (int r = 0; r < 4; ++r){
          int j = j0 + js*16 + quad*4 + r;
          outp[((size_t)n*C_ + j)*L_ + l] = f2bf(acc[js][ls][r] + bb[r]);
        }
      } else {
        union { ushort u[4]; uint2v v; } pk;
#pragma unroll
        for (int r = 0; r < 4; ++r) pk.u[r] = f2bf(acc[js][ls][r] + bb[r]);
        *(uint2v*)(outp + ((size_t)n*L_ + l)*CK_ + j0 + js*16 + quad*4) = pk.v;
      }
    }
  }
}

// ---------- stats: partial row/col sums of exp(cor) ----------
__global__ __launch_bounds__(256) void stats_kernel(
    const ushort* __restrict__ k1t, const ushort* __restrict__ k2t,
    float* __restrict__ S1part, float* __restrict__ S2part){
  int n = blockIdx.z;
  int m0 = blockIdx.x * 128, l0 = blockIdx.y * 128;
  int t = threadIdx.x, w = t >> 6, lane = t & 63, quad = lane >> 4, low = lane & 15;
  __shared__ float rowsum[128];
  __shared__ float colsum[4][128];
  const ushort* ka = k1t + (size_t)n * L_ * CK_;
  const ushort* kb = k2t + (size_t)n * L_ * CK_;
  short8 a[2], b[8];
#pragma unroll
  for (int lt = 0; lt < 2; ++lt)
    a[lt] = *(const short8*)(ka + (size_t)(l0 + w*32 + lt*16 + low)*CK_ + quad*8);
#pragma unroll
  for (int mt = 0; mt < 8; ++mt)
    b[mt] = *(const short8*)(kb + (size_t)(m0 + mt*16 + low)*CK_ + quad*8);
  float rp[2][4] = {}; float cp[8] = {};
  const f32x4 zero = {0.f, 0.f, 0.f, 0.f};
#pragma unroll
  for (int lt = 0; lt < 2; ++lt)
#pragma unroll
    for (int mt = 0; mt < 8; ++mt){
      f32x4 e = mfma16(a[lt], b[mt], zero);
#pragma unroll
      for (int r = 0; r < 4; ++r){
        float v = __builtin_amdgcn_exp2f(e[r] * 1.44269504088896f);
        rp[lt][r] += v;
        cp[mt] += v;
      }
    }
#pragma unroll
  for (int lt = 0; lt < 2; ++lt)
#pragma unroll
    for (int r = 0; r < 4; ++r){
      float v = rp[lt][r];
      v += __shfl_xor(v, 1); v += __shfl_xor(v, 2);
      v += __shfl_xor(v, 4); v += __shfl_xor(v, 8);
      if (low == 0) rowsum[w*32 + lt*16 + quad*4 + r] = v;
    }
#pragma unroll
  for (int mt = 0; mt < 8; ++mt){
    float v = cp[mt];
    v += __shfl_xor(v, 16); v += __shfl_xor(v, 32);
    if (quad == 0) colsum[w][mt*16 + low] = v;
  }
  __syncthreads();
  if (t < 128)
    S1part[((size_t)n*32 + blockIdx.x)*L_ + l0 + t] = rowsum[t];
  else {
    int m = t - 128;
    S2part[((size_t)n*32 + blockIdx.y)*L_ + m0 + m] =
        colsum[0][m] + colsum[1][m] + colsum[2][m] + colsum[3][m];
  }
}

// ---------- reduce partials -> lsv = log2(1/S) = -log2(S) ----------
// (r-kernel computes P = exp2(cor*log2e + lsv) = exp(cor)/S)
__global__ __launch_bounds__(256) void reduce_inv_kernel(
    const float* __restrict__ S1part, const float* __restrict__ S2part,
    float* __restrict__ invS1, float* __restrict__ invS2){
  int idx = blockIdx.x * 256 + threadIdx.x;          // 0..16383
  int which = idx >> 13;
  int r = idx & 8191;                                // n*L + l
  int n = r >> 12, l = r & 4095;
  const float* P = which ? S2part : S1part;
  float s = 0.f;
#pragma unroll
  for (int j = 0; j < 32; ++j) s += P[((size_t)n*32 + j)*L_ + l];
  (which ? invS2 : invS1)[(size_t)n*L_ + l] = -__builtin_amdgcn_logf(s);
}

#define LOG2E_ 1.44269504088896f

// E phase: P chunk rows [w*32, w*32+32) -> LDS transposed [q][p] bf16
__device__ __forceinline__ void e_phase(ushort (*buf)[144],
    short8 a0, short8 a1, f32x4 s0, f32x4 s1, const short8* be,
    int w, int quad, int low){
  const f32x4 zero = {0.f, 0.f, 0.f, 0.f};
#pragma unroll
  for (int ps = 0; ps < 2; ++ps){
    short8 a = ps ? a1 : a0;
    f32x4 sv = ps ? s1 : s0;
#pragma unroll
    for (int qs = 0; qs < 4; ++qs){
      f32x4 e = mfma16(a, be[qs], zero);
      float p0 = __builtin_amdgcn_exp2f(__fmaf_rn(e[0], LOG2E_, sv[0]));
      float p1 = __builtin_amdgcn_exp2f(__fmaf_rn(e[1], LOG2E_, sv[1]));
      float p2 = __builtin_amdgcn_exp2f(__fmaf_rn(e[2], LOG2E_, sv[2]));
      float p3 = __builtin_amdgcn_exp2f(__fmaf_rn(e[3], LOG2E_, sv[3]));
      union { __hip_bfloat162 h[2]; uint2v v; } pk;
      pk.h[0] = __float22bfloat162_rn(make_float2(p0, p1));
      pk.h[1] = __float22bfloat162_rn(make_float2(p2, p3));
      *(uint2v*)&buf[qs*16 + low][w*32 + ps*16 + quad*4] = pk.v;
    }
  }
}

// main phase: acc[c,q] += V[c,p] * P[p,q]
__device__ __forceinline__ void main_phase(const ushort (*buf)[144],
    const short8* v, f32x4 (*acc)[4], int quad, int low){
#pragma unroll
  for (int ks = 0; ks < 4; ++ks){
    short8 bb[4];
#pragma unroll
    for (int qs = 0; qs < 4; ++qs)
      bb[qs] = *(const short8*)&buf[qs*16 + low][ks*32 + quad*8];
#pragma unroll
    for (int cs = 0; cs < 2; ++cs)
#pragma unroll
      for (int qs = 0; qs < 4; ++qs)
        acc[cs][qs] = mfma16(v[ks*2 + cs], bb[qs], acc[cs][qs]);
  }
}

// ---------- unified flash r-kernel v4 ----------
// Same topology as v3 (q=64, c=128, grid 512 = 2 blocks/CU, dbuf ptile,
// one barrier per chunk) but the pipeline uses ONLY compile-time-indexed
// named register sets (v3's runtime-parity arrays were demoted to scratch:
// VGPR=108 < needed 136+ -> spill traffic was the 6600cy/chunk stall).
// Manual two-body loop: body A consumes set A / buf0, prefetches set B;
// body B consumes set B / buf1, prefetches set A.
__global__ __launch_bounds__(256, 2) void cross_attn_r_kernel(
    const ushort* __restrict__ k1t, const ushort* __restrict__ k2t,
    const ushort* __restrict__ v1,  const ushort* __restrict__ v2,
    const float* __restrict__ invS1, const float* __restrict__ invS2,
    const float* __restrict__ x1, const float* __restrict__ x2,
    float* __restrict__ out){
  int z = blockIdx.z; int which = z >> 1; int n = z & 1;
  const ushort* kA = which ? k2t : k1t;
  const ushort* kB = which ? k1t : k2t;
  const ushort* V  = which ? v2  : v1;
  const float* iS  = which ? invS2 : invS1;
  const float* X   = which ? x2 : x1;
  float* O = out + (size_t)which * N_ * C_ * L_;
  int q0 = blockIdx.x * 64, c0 = blockIdx.y * 128;
  int t = threadIdx.x, w = t >> 6, lane = t & 63, quad = lane >> 4, low = lane & 15;
  __shared__ __align__(16) ushort ptile[2][64][144];
  const ushort* kAn = kA + (size_t)n * L_ * CK_;
  const ushort* kBn = kB + (size_t)n * L_ * CK_;
  const ushort* Vn  = V  + (size_t)n * C_ * L_;
  const float*  iSn = iS + (size_t)n * L_;

  // lane-invariant base pointers (p is the only runtime offset)
  const ushort* kA_base = kAn + (size_t)(w*32 + low) * CK_ + quad * 8;
  const float*  sv_base = iSn + w*32 + quad * 4;
  const ushort* V_base  = Vn + (size_t)(c0 + w*32 + low) * L_ + quad * 8;

  // E-phase B operand (q rows of kB) is chunk-invariant: preload once.
  short8 be[4];
#pragma unroll
  for (int qs = 0; qs < 4; ++qs)
    be[qs] = *(const short8*)(kBn + (size_t)(q0 + qs*16 + low) * CK_ + quad * 8);

  f32x4 acc[2][4] = {};

  // named prefetch sets (all literal-indexed)
  short8 a0A, a1A, a0B, a1B;
  f32x4  s0A, s1A, s0B, s1B;
  short8 vA[8], vB[8];

#define LOAD_SET(A0, A1, S0, S1, VV, P) do{                                   \
    A0 = *(const short8*)(kA_base + (size_t)(P) * CK_);                       \
    A1 = *(const short8*)(kA_base + (size_t)((P) + 16) * CK_);                \
    S0 = *(const f32x4*)(sv_base + (P));                                      \
    S1 = *(const f32x4*)(sv_base + (P) + 16);                                 \
    VV[0] = *(const short8*)(V_base + (P) + 0*32);                            \
    VV[2] = *(const short8*)(V_base + (P) + 1*32);                            \
    VV[4] = *(const short8*)(V_base + (P) + 2*32);                            \
    VV[6] = *(const short8*)(V_base + (P) + 3*32);                            \
    VV[1] = *(const short8*)(V_base + (size_t)16*L_ + (P) + 0*32);            \
    VV[3] = *(const short8*)(V_base + (size_t)16*L_ + (P) + 1*32);            \
    VV[5] = *(const short8*)(V_base + (size_t)16*L_ + (P) + 2*32);            \
    VV[7] = *(const short8*)(V_base + (size_t)16*L_ + (P) + 3*32);            \
  }while(0)

  LOAD_SET(a0A, a1A, s0A, s1A, vA, 0);

  for (int kk = 0; kk < L_ / 256; ++kk){
    int pB  = (2*kk + 1) * 128;
    int pA2 = ((2*kk + 2) & 31) * 128;   // wraps to 0 on last iter (harmless)
    // ---- body A: chunk 2kk in ptile[0]; prefetch set B
    e_phase(ptile[0], a0A, a1A, s0A, s1A, be, w, quad, low);
    LOAD_SET(a0B, a1B, s0B, s1B, vB, pB);
    __syncthreads();
    main_phase(ptile[0], vA, acc, quad, low);
    // ---- body B: chunk 2kk+1 in ptile[1]; prefetch set A
    e_phase(ptile[1], a0B, a1B, s0B, s1B, be, w, quad, low);
    LOAD_SET(a0A, a1A, s0A, s1A, vA, pA2);
    __syncthreads();
    main_phase(ptile[1], vB, acc, quad, low);
  }
#undef LOAD_SET

  // --- epilogue: out = x + acc
#pragma unroll
  for (int cs = 0; cs < 2; ++cs)
#pragma unroll
    for (int qs = 0; qs < 4; ++qs){
      int cb = c0 + w*32 + cs*16 + quad*4;
      int q = q0 + qs*16 + low;
#pragma unroll
      for (int r = 0; r < 4; ++r){
        size_t idx = ((size_t)n * C_ + cb + r) * L_ + q;
        O[idx] = X[idx] + acc[cs][qs][r];
      }
    }
}

extern "C" void kernel_launch(void* const* d_in, const int* in_sizes, int n_in,
                              void* d_out, int out_size, void* d_ws, size_t ws_size,
                              hipStream_t stream) {
  const float* x1  = (const float*)d_in[0];
  const float* x2  = (const float*)d_in[1];
  const float* Wk1 = (const float*)d_in[2];
  const float* bk1 = (const float*)d_in[3];
  const float* Wk2 = (const float*)d_in[4];
  const float* bk2 = (const float*)d_in[5];
  const float* Wv1 = (const float*)d_in[6];
  const float* bv1 = (const float*)d_in[7];
  const float* Wv2 = (const float*)d_in[8];
  const float* bv2 = (const float*)d_in[9];

  char* ws = (char*)d_ws;
  size_t off = 0;
  auto carve = [&](size_t bytes) -> void* {
    void* p = ws + off; off += (bytes + 255) & ~(size_t)255; return p;
  };
  ushort* xT1   = (ushort*)carve((size_t)N_*L_*C_*2);
  ushort* xT2   = (ushort*)carve((size_t)N_*L_*C_*2);
  ushort* Wk1b  = (ushort*)carve((size_t)CK_*C_*2);
  ushort* Wk2b  = (ushort*)carve((size_t)CK_*C_*2);
  ushort* Wv1b  = (ushort*)carve((size_t)C_*C_*2);
  ushort* Wv2b  = (ushort*)carve((size_t)C_*C_*2);
  ushort* k1t   = (ushort*)carve((size_t)N_*L_*CK_*2);
  ushort* k2t   = (ushort*)carve((size_t)N_*L_*CK_*2);
  ushort* v1    = (ushort*)carve((size_t)N_*C_*L_*2);
  ushort* v2    = (ushort*)carve((size_t)N_*C_*L_*2);
  float*  S1p   = (float*)carve((size_t)N_*32*L_*4);
  float*  S2p   = (float*)carve((size_t)N_*32*L_*4);
  float*  invS1 = (float*)carve((size_t)N_*L_*4);
  float*  invS2 = (float*)carve((size_t)N_*L_*4);

  convert_x_kernel<<<dim3(L_/64, C_/128, 4), 256, 0, stream>>>(x1, x2, xT1, xT2);
  convert_w_kernel<<<dim3((2*CK_*C_ + 2*C_*C_) / 256), 256, 0, stream>>>(
      Wk1, Wk2, Wv1, Wv2, Wk1b, Wk2b, Wv1b, Wv2b);
  proj_kernel<<<dim3(L_/128, 18, N_), 256, 0, stream>>>(
      xT1, xT2, Wk1b, Wk2b, Wv1b, Wv2b, bk1, bk2, bv1, bv2, k1t, k2t, v1, v2);
  stats_kernel<<<dim3(L_/128, L_/128, N_), 256, 0, stream>>>(k1t, k2t, S1p, S2p);
  reduce_inv_kernel<<<dim3(2*N_*L_/256), 256, 0, stream>>>(S1p, S2p, invS1, invS2);
  cross_attn_r_kernel<<<dim3(L_/64, C_/128, 2*N_), 256, 0, stream>>>(
      k1t, k2t, v1, v2, invS1, invS2, x1, x2, (float*)d_out);
}